// Round 5
// baseline (239.500 us; speedup 1.0000x reference)
//
#include <hip/hip_runtime.h>

#define HDIM 256
#define NREL 16
#define NBLK 128
#define APAD 260   // aggL row stride (f32): %4==0 (align), %32==4 (conflict-free epilogue)

typedef __attribute__((ext_vector_type(8))) short bf16x8;
typedef __attribute__((ext_vector_type(8))) unsigned short u16x8;
typedef __attribute__((ext_vector_type(4))) float f32x4;

__device__ __forceinline__ unsigned short f2bf(float f) {
    unsigned int u = __float_as_uint(f);
    u = (u + 0x7FFFu + ((u >> 16) & 1u)) >> 16;   // RNE
    return (unsigned short)u;
}
__device__ __forceinline__ float bf2f(unsigned short s) {
    return __uint_as_float((unsigned int)s << 16);
}

// ---------------- convert x->bf16, loop_w -> bf16 transposed, zero deg ----------------
__global__ void convert_kernel(const float* __restrict__ x, unsigned short* __restrict__ xb,
                               const float* __restrict__ lw1, unsigned short* __restrict__ w1t,
                               const float* __restrict__ lw2, unsigned short* __restrict__ w2t,
                               int* __restrict__ deg, int nx, int M) {
    const int total = nx + 131072 + M;
    for (int i = blockIdx.x * blockDim.x + threadIdx.x; i < total; i += gridDim.x * blockDim.x) {
        if (i < nx) {
            xb[i] = f2bf(x[i]);
        } else if (i < nx + 65536) {
            int j = i - nx; int n = j >> 8, k = j & 255;
            w1t[j] = f2bf(lw1[k * HDIM + n]);   // W^T[n][k]
        } else if (i < nx + 131072) {
            int j = i - nx - 65536; int n = j >> 8, k = j & 255;
            w2t[j] = f2bf(lw2[k * HDIM + n]);
        } else {
            deg[i - nx - 131072] = 0;
        }
    }
}

// ---------------- counting-sort by dst ----------------
__global__ void hist_kernel(const int* __restrict__ dst, int* __restrict__ deg, int E) {
    for (int e = blockIdx.x * blockDim.x + threadIdx.x; e < E; e += gridDim.x * blockDim.x)
        atomicAdd(&deg[dst[e]], 1);
}

__global__ __launch_bounds__(1024) void scan_kernel(const int* __restrict__ deg,
                                                    int* __restrict__ start,
                                                    int* __restrict__ cnt, int N) {
    __shared__ int part[1024];
    const int t = threadIdx.x;
    const int CH = (N + 1023) >> 10;
    const int c0 = t * CH;
    int sum = 0;
    for (int i = 0; i < CH; ++i) { int idx = c0 + i; if (idx < N) sum += deg[idx]; }
    part[t] = sum;
    __syncthreads();
    for (int off = 1; off < 1024; off <<= 1) {
        int v = (t >= off) ? part[t - off] : 0;
        __syncthreads();
        part[t] += v;
        __syncthreads();
    }
    int run = (t > 0) ? part[t - 1] : 0;
    for (int i = 0; i < CH; ++i) {
        int idx = c0 + i;
        if (idx < N) { start[idx] = run; cnt[idx] = run; run += deg[idx]; }
    }
    if (t == 1023) start[N] = part[1023];
}

__global__ void scatter_kernel(const int* __restrict__ src, const int* __restrict__ dst,
                               const int* __restrict__ et, const float* __restrict__ norm,
                               int* __restrict__ cnt, int2* __restrict__ epack, int E) {
    for (int e = blockIdx.x * blockDim.x + threadIdx.x; e < E; e += gridDim.x * blockDim.x) {
        int d = dst[e];
        int pos = atomicAdd(&cnt[d], 1);
        epack[pos] = make_int2(src[e] * NREL + et[e], __float_as_int(norm[e]));
    }
}

// ---------------- per-edge micro-matmul: lane owns blocks b0..b0+3 (8 channels) ----------------
__device__ __forceinline__ void edge_acc(float acc[8], u16x8 xq, int r, float nm,
                                         const float* __restrict__ wt, int b0) {
    const float4 w00 = *(const float4*)(wt + (r * 4 + 0) * NBLK + b0); // i=0,io=0
    const float4 w01 = *(const float4*)(wt + (r * 4 + 1) * NBLK + b0); // i=0,io=1
    const float4 w10 = *(const float4*)(wt + (r * 4 + 2) * NBLK + b0); // i=1,io=0
    const float4 w11 = *(const float4*)(wt + (r * 4 + 3) * NBLK + b0); // i=1,io=1
    const float x0 = bf2f(xq[0]), x1 = bf2f(xq[1]), x2 = bf2f(xq[2]), x3 = bf2f(xq[3]);
    const float x4 = bf2f(xq[4]), x5 = bf2f(xq[5]), x6 = bf2f(xq[6]), x7 = bf2f(xq[7]);
    acc[0] = fmaf(nm, fmaf(x0, w00.x, x1 * w10.x), acc[0]);
    acc[1] = fmaf(nm, fmaf(x0, w01.x, x1 * w11.x), acc[1]);
    acc[2] = fmaf(nm, fmaf(x2, w00.y, x3 * w10.y), acc[2]);
    acc[3] = fmaf(nm, fmaf(x2, w01.y, x3 * w11.y), acc[3]);
    acc[4] = fmaf(nm, fmaf(x4, w00.z, x5 * w10.z), acc[4]);
    acc[5] = fmaf(nm, fmaf(x4, w01.z, x5 * w11.z), acc[5]);
    acc[6] = fmaf(nm, fmaf(x6, w00.w, x7 * w10.w), acc[6]);
    acc[7] = fmaf(nm, fmaf(x6, w01.w, x7 * w11.w), acc[7]);
}

// ---------------- fused layer: aggregate 32 dst rows into LDS, then MFMA self-loop ----------------
// Block = 512 thr = 8 waves, covers rows [mblk, mblk+32).
// Phase A: wave wv aggregates nodes mblk+4wv .. +3 (dual-edge: lanes<32 even edge, lanes>=32 odd edge).
// Phase B: wave wv computes cols [32wv, 32wv+32) of out[mblk..mblk+32] = A@W^T + bias + aggL (+relu).
template <int RELU_BF>
__global__ __launch_bounds__(512) void layer_kernel(
    const unsigned short* __restrict__ xin,   // bf16 [M,256]: gather source AND GEMM A
    const int2* __restrict__ epack,
    const int* __restrict__ start,
    const float* __restrict__ w,              // (R,B,2,2) f32 relation weights
    const unsigned short* __restrict__ BT,    // bf16 [256,256], BT[n][k] = loop_w[k][n]
    const float* __restrict__ bias,
    unsigned short* __restrict__ hOut,        // RELU_BF=1: bf16 out
    float* __restrict__ fOut,                 // RELU_BF=0: f32 out
    int M)
{
    __shared__ float wt[NREL * 512];          // [r][i][io][b]
    __shared__ float aggL[32 * APAD];

    for (int j = threadIdx.x; j < NREL * 512; j += blockDim.x) {
        int io = j & 1, i = (j >> 1) & 1, b = (j >> 2) & (NBLK - 1), r = j >> 9;
        wt[((r * 2 + i) * 2 + io) * NBLK + b] = w[j];
    }
    __syncthreads();

    const int t = threadIdx.x;
    const int wv = t >> 6;
    const int l  = t & 63;
    const int hl  = l >> 5;          // half: 0 = even edge, 1 = odd edge
    const int m32 = l & 31;
    const int c2  = m32 * 8;         // 8-channel base
    const int b0  = m32 * 4;         // 4-block base
    const int mblk = blockIdx.x * 32;

    // ---- Phase A ----
    #pragma unroll
    for (int tn = 0; tn < 4; ++tn) {
        const int lrow = wv * 4 + tn;
        const int d = mblk + lrow;
        float acc[8] = {0.f, 0.f, 0.f, 0.f, 0.f, 0.f, 0.f, 0.f};
        if (d < M) {
            const int s0 = start[d], s1 = start[d + 1];
            int idx = s0;
            for (; idx + 4 <= s1; idx += 4) {
                const int2 pa0 = epack[idx + 0], pa1 = epack[idx + 1];
                const int2 pb0 = epack[idx + 2], pb1 = epack[idx + 3];
                const int   ea = hl ? pa1.x : pa0.x;
                const float na = __int_as_float(hl ? pa1.y : pa0.y);
                const int   eb = hl ? pb1.x : pb0.x;
                const float nb = __int_as_float(hl ? pb1.y : pb0.y);
                const u16x8 xa = *(const u16x8*)(xin + (size_t)(ea >> 4) * HDIM + c2);
                const u16x8 xv = *(const u16x8*)(xin + (size_t)(eb >> 4) * HDIM + c2);
                edge_acc(acc, xa, ea & (NREL - 1), na, wt, b0);
                edge_acc(acc, xv, eb & (NREL - 1), nb, wt, b0);
            }
            if (idx + 2 <= s1) {
                const int2 p0 = epack[idx], p1 = epack[idx + 1];
                const int   e = hl ? p1.x : p0.x;
                const float n = __int_as_float(hl ? p1.y : p0.y);
                const u16x8 xa = *(const u16x8*)(xin + (size_t)(e >> 4) * HDIM + c2);
                edge_acc(acc, xa, e & (NREL - 1), n, wt, b0);
                idx += 2;
            }
            if (idx < s1) {
                const int2 p0 = epack[idx];
                const float n = hl ? 0.f : __int_as_float(p0.y);   // high half contributes 0
                const u16x8 xa = *(const u16x8*)(xin + (size_t)(p0.x >> 4) * HDIM + c2);
                edge_acc(acc, xa, p0.x & (NREL - 1), n, wt, b0);
            }
        }
        // combine halves: both halves end with full sums of their 8 channels
        #pragma unroll
        for (int k = 0; k < 8; ++k) acc[k] += __shfl_xor(acc[k], 32);
        const int col = c2 + 4 * hl;
        *(float4*)(&aggL[lrow * APAD + col]) =
            make_float4(acc[4 * hl + 0], acc[4 * hl + 1], acc[4 * hl + 2], acc[4 * hl + 3]);
    }
    __syncthreads();

    // ---- Phase B: MFMA ----
    const int lr = l & 15;
    const int lk = l >> 4;
    const int n0 = wv * 32;

    f32x4 acc2[2][2] = {};
    const unsigned short* arow0 = xin + (size_t)(mblk + lr) * HDIM + lk * 8;
    const unsigned short* arow1 = arow0 + 16 * HDIM;
    const unsigned short* brow  = BT + (size_t)(n0 + lr) * HDIM + lk * 8;

    #pragma unroll
    for (int ks = 0; ks < 8; ++ks) {
        const int k0 = ks * 32;
        const bf16x8 a0 = *(const bf16x8*)(arow0 + k0);
        const bf16x8 a1 = *(const bf16x8*)(arow1 + k0);
        #pragma unroll
        for (int j = 0; j < 2; ++j) {
            const bf16x8 b = *(const bf16x8*)(brow + j * 16 * HDIM + k0);
            acc2[0][j] = __builtin_amdgcn_mfma_f32_16x16x32_bf16(a0, b, acc2[0][j], 0, 0, 0);
            acc2[1][j] = __builtin_amdgcn_mfma_f32_16x16x32_bf16(a1, b, acc2[1][j], 0, 0, 0);
        }
    }

    #pragma unroll
    for (int i = 0; i < 2; ++i) {
        #pragma unroll
        for (int j = 0; j < 2; ++j) {
            const int gn = n0 + 16 * j + lr;
            const float bv = bias[gn];
            #pragma unroll
            for (int q = 0; q < 4; ++q) {
                const int row = 16 * i + 4 * lk + q;
                const int gm  = mblk + row;
                if (gm < M) {
                    float v = acc2[i][j][q] + bv + aggL[row * APAD + gn];
                    if (RELU_BF) {
                        hOut[(size_t)gm * HDIM + gn] = f2bf(fmaxf(v, 0.f));
                    } else {
                        fOut[(size_t)gm * HDIM + gn] = v;
                    }
                }
            }
        }
    }
}

extern "C" void kernel_launch(void* const* d_in, const int* in_sizes, int n_in,
                              void* d_out, int out_size, void* d_ws, size_t ws_size,
                              hipStream_t stream) {
    const float* x    = (const float*)d_in[0];
    const int*   src  = (const int*)d_in[1];
    const int*   dst  = (const int*)d_in[2];
    const int*   et   = (const int*)d_in[3];
    const float* norm = (const float*)d_in[4];
    const float* w1   = (const float*)d_in[5];
    const float* lw1  = (const float*)d_in[6];
    const float* b1   = (const float*)d_in[7];
    const float* w2   = (const float*)d_in[8];
    const float* lw2  = (const float*)d_in[9];
    const float* b2   = (const float*)d_in[10];

    const int M = in_sizes[0] / HDIM;   // 20000
    const int E = in_sizes[1];          // 320000

    float* out = (float*)d_out;
    char*  ws  = (char*)d_ws;

    // ws layout (~23.6 MB)
    size_t off = 0;
    unsigned short* xb  = (unsigned short*)(ws + off); off += (size_t)M * HDIM * 2;
    unsigned short* h2b = (unsigned short*)(ws + off); off += (size_t)M * HDIM * 2;
    unsigned short* w1t = (unsigned short*)(ws + off); off += 65536 * 2;
    unsigned short* w2t = (unsigned short*)(ws + off); off += 65536 * 2;
    int* start = (int*)(ws + off);  off += (size_t)(M + 1) * 4; off = (off + 15) & ~15ull;
    int* cnt   = (int*)(ws + off);  off += (size_t)M * 4;       off = (off + 15) & ~15ull;
    int* deg   = (int*)(ws + off);  off += (size_t)M * 4;       off = (off + 15) & ~15ull;
    int2* epack = (int2*)(ws + off); off += (size_t)E * 8;
    (void)ws_size;

    // ---- preprocess ----
    convert_kernel<<<2048, 256, 0, stream>>>(x, xb, lw1, w1t, lw2, w2t, deg, M * HDIM, M);
    hist_kernel<<<512, 256, 0, stream>>>(dst, deg, E);
    scan_kernel<<<1, 1024, 0, stream>>>(deg, start, cnt, M);
    scatter_kernel<<<512, 256, 0, stream>>>(src, dst, et, norm, cnt, epack, E);

    const int gblk = (M + 31) / 32;

    // Layer 1: h2b = bf16(relu(agg1 + b1 + xb@lw1))
    layer_kernel<1><<<gblk, 512, 0, stream>>>(xb, epack, start, w1, w1t, b1, h2b, nullptr, M);
    // Layer 2: out = agg2 + b2 + h2b@lw2
    layer_kernel<0><<<gblk, 512, 0, stream>>>(h2b, epack, start, w2, w2t, b2, nullptr, out, M);
}

// Round 6
// 227.612 us; speedup vs baseline: 1.0522x; 1.0522x over previous
//
#include <hip/hip_runtime.h>

#define HDIM 256
#define NREL 16
#define NBLK 128
#define AWPB 8   // waves (nodes) per agg block

typedef __attribute__((ext_vector_type(8))) short bf16x8;
typedef __attribute__((ext_vector_type(4))) float f32x4;

__device__ __forceinline__ unsigned short f2bf(float f) {
    unsigned int u = __float_as_uint(f);
    u = (u + 0x7FFFu + ((u >> 16) & 1u)) >> 16;   // RNE
    return (unsigned short)u;
}

// ---------------- convert x->bf16, loop_w -> bf16 transposed, zero deg ----------------
__global__ void convert_kernel(const float* __restrict__ x, unsigned short* __restrict__ xb,
                               const float* __restrict__ lw1, unsigned short* __restrict__ w1t,
                               const float* __restrict__ lw2, unsigned short* __restrict__ w2t,
                               int* __restrict__ deg, int nx, int M) {
    const int total = nx + 131072 + M;
    for (int i = blockIdx.x * blockDim.x + threadIdx.x; i < total; i += gridDim.x * blockDim.x) {
        if (i < nx) {
            xb[i] = f2bf(x[i]);
        } else if (i < nx + 65536) {
            int j = i - nx; int n = j >> 8, k = j & 255;
            w1t[j] = f2bf(lw1[k * HDIM + n]);   // W^T[n][k]
        } else if (i < nx + 131072) {
            int j = i - nx - 65536; int n = j >> 8, k = j & 255;
            w2t[j] = f2bf(lw2[k * HDIM + n]);
        } else {
            deg[i - nx - 131072] = 0;
        }
    }
}

// ---------------- counting-sort by dst ----------------
__global__ void hist_kernel(const int* __restrict__ dst, int* __restrict__ deg, int E) {
    for (int e = blockIdx.x * blockDim.x + threadIdx.x; e < E; e += gridDim.x * blockDim.x)
        atomicAdd(&deg[dst[e]], 1);
}

__global__ __launch_bounds__(1024) void scan_kernel(const int* __restrict__ deg,
                                                    int* __restrict__ start,
                                                    int* __restrict__ cnt, int N) {
    __shared__ int part[1024];
    const int t = threadIdx.x;
    const int CH = (N + 1023) >> 10;
    const int c0 = t * CH;
    int sum = 0;
    for (int i = 0; i < CH; ++i) { int idx = c0 + i; if (idx < N) sum += deg[idx]; }
    part[t] = sum;
    __syncthreads();
    for (int off = 1; off < 1024; off <<= 1) {
        int v = (t >= off) ? part[t - off] : 0;
        __syncthreads();
        part[t] += v;
        __syncthreads();
    }
    int run = (t > 0) ? part[t - 1] : 0;
    for (int i = 0; i < CH; ++i) {
        int idx = c0 + i;
        if (idx < N) { start[idx] = run; cnt[idx] = run; run += deg[idx]; }
    }
    if (t == 1023) start[N] = part[1023];
}

__global__ void scatter_kernel(const int* __restrict__ src, const int* __restrict__ dst,
                               const int* __restrict__ et, const float* __restrict__ norm,
                               int* __restrict__ cnt, int2* __restrict__ epack, int E) {
    for (int e = blockIdx.x * blockDim.x + threadIdx.x; e < E; e += gridDim.x * blockDim.x) {
        int d = dst[e];
        int pos = atomicAdd(&cnt[d], 1);
        epack[pos] = make_int2(src[e] * NREL + et[e], __float_as_int(norm[e]));
    }
}

// ---------------- per-edge micro-matmul: lane owns blocks b0..b0+3 (8 channels) ----------------
// xa: 4 uints, each = packed bf16 pair (x[2b] lo, x[2b+1] hi)
// w0/w1: packed weight pairs for io=0 / io=1: uint = (w[b,0,io] lo, w[b,1,io] hi)
__device__ __forceinline__ void accum8(float acc[8], uint4 xa, uint4 w0, uint4 w1, float nm) {
    const unsigned int xs[4] = {xa.x, xa.y, xa.z, xa.w};
    const unsigned int a0[4] = {w0.x, w0.y, w0.z, w0.w};
    const unsigned int a1[4] = {w1.x, w1.y, w1.z, w1.w};
    #pragma unroll
    for (int k = 0; k < 4; ++k) {
        const float x0  = __uint_as_float(xs[k] << 16);
        const float x1  = __uint_as_float(xs[k] & 0xFFFF0000u);
        const float w00 = __uint_as_float(a0[k] << 16);
        const float w10 = __uint_as_float(a0[k] & 0xFFFF0000u);
        const float w01 = __uint_as_float(a1[k] << 16);
        const float w11 = __uint_as_float(a1[k] & 0xFFFF0000u);
        acc[2 * k]     = fmaf(nm, fmaf(x0, w00, x1 * w10), acc[2 * k]);
        acc[2 * k + 1] = fmaf(nm, fmaf(x0, w01, x1 * w11), acc[2 * k + 1]);
    }
}

// process 2 edges (one per half-wave) given int4 q = (e_even, n_even, e_odd, n_odd)
__device__ __forceinline__ void edge2(float acc[8], const unsigned short* __restrict__ xin,
                                      const unsigned int* wp, int4 q, int hl, int c2, int b0) {
    const int   e  = hl ? q.z : q.x;
    const float nm = __int_as_float(hl ? q.w : q.y);
    const uint4 xa = *(const uint4*)(xin + (size_t)(e >> 4) * HDIM + c2);
    const int r = e & (NREL - 1);
    const uint4 w0 = *(const uint4*)(wp + (r * 2 + 0) * NBLK + b0);
    const uint4 w1 = *(const uint4*)(wp + (r * 2 + 1) * NBLK + b0);
    accum8(acc, xa, w0, w1, nm);
}

// ---------------- pull aggregation: wave-per-node, dual-edge (2 edges per wave-step) ----------------
__global__ __launch_bounds__(512) void agg_kernel(
    const unsigned short* __restrict__ xin,  // bf16 [M,256]
    const int2* __restrict__ epack,
    const int* __restrict__ start,
    const float* __restrict__ w,             // (R,B,2,2) f32
    float* __restrict__ agg,
    int N)
{
    // packed bf16 weight pairs: wp[(r*2+io)*128 + b] = (bf16(w[r,b,0,io]), bf16(w[r,b,1,io]))
    __shared__ unsigned int wp[NREL * 2 * NBLK];   // 16 KB
    for (int j = threadIdx.x; j < NREL * 256; j += blockDim.x) {
        int r = j >> 8, t8 = j & 255, b = t8 >> 1, io = t8 & 1;
        float w0 = w[r * 512 + b * 4 + io];
        float w1 = w[r * 512 + b * 4 + 2 + io];
        wp[(r * 2 + io) * NBLK + b] = (unsigned)f2bf(w0) | ((unsigned)f2bf(w1) << 16);
    }
    __syncthreads();

    const int wv  = threadIdx.x >> 6;
    const int l   = threadIdx.x & 63;
    const int hl  = l >> 5;          // 0: even edge, 1: odd edge
    const int m32 = l & 31;
    const int c2  = m32 * 8;         // channel base (8 channels)
    const int b0  = m32 * 4;         // block base (4 blocks)

    for (int d = blockIdx.x * AWPB + wv; d < N; d += gridDim.x * AWPB) {
        const int s0 = start[d], s1 = start[d + 1];
        float acc[8] = {0.f, 0.f, 0.f, 0.f, 0.f, 0.f, 0.f, 0.f};
        int idx = s0;
        for (; idx + 8 <= s1; idx += 8) {
            const int4 q0 = *(const int4*)&epack[idx + 0];
            const int4 q1 = *(const int4*)&epack[idx + 2];
            const int4 q2 = *(const int4*)&epack[idx + 4];
            const int4 q3 = *(const int4*)&epack[idx + 6];
            edge2(acc, xin, wp, q0, hl, c2, b0);
            edge2(acc, xin, wp, q1, hl, c2, b0);
            edge2(acc, xin, wp, q2, hl, c2, b0);
            edge2(acc, xin, wp, q3, hl, c2, b0);
        }
        for (; idx + 2 <= s1; idx += 2) {
            const int4 q = *(const int4*)&epack[idx];
            edge2(acc, xin, wp, q, hl, c2, b0);
        }
        if (idx < s1) {
            const int2 p = epack[idx];
            const int4 q = make_int4(p.x, p.y, p.x, 0);   // odd half: nm=0
            edge2(acc, xin, wp, q, hl, c2, b0);
        }
        #pragma unroll
        for (int k = 0; k < 8; ++k) acc[k] += __shfl_xor(acc[k], 32);
        const float4 o = hl ? make_float4(acc[4], acc[5], acc[6], acc[7])
                            : make_float4(acc[0], acc[1], acc[2], acc[3]);
        *(float4*)(agg + (size_t)d * HDIM + c2 + 4 * hl) = o;
    }
}

// ---------------- MFMA self-loop GEMM: out = [relu](A @ W^T + bias + agg) ----------------
// Block = 256 thr = 4 waves; 32 m-rows x 256 n-cols (wave wv: n0 = 64*wv).
template <int RELU_BF>
__global__ __launch_bounds__(256) void mfma_gemm(
    const unsigned short* __restrict__ A,     // [M,256] bf16
    const unsigned short* __restrict__ BT,    // [256,256] bf16, BT[n][k] = W[k][n]
    const float* __restrict__ bias,
    const float* __restrict__ agg,
    float* __restrict__ outF,
    unsigned short* __restrict__ hb,
    int M)
{
    const int wv = threadIdx.x >> 6;
    const int l  = threadIdx.x & 63;
    const int lr = l & 15;
    const int lk = l >> 4;
    const int mblk = blockIdx.x * 32;
    const int n0 = wv * 64;

    f32x4 acc[2][4] = {};

    const unsigned short* arow0 = A + (size_t)(mblk + lr) * HDIM + lk * 8;
    const unsigned short* arow1 = arow0 + 16 * HDIM;
    const unsigned short* brow0 = BT + (size_t)(n0 + lr) * HDIM + lk * 8;

    #pragma unroll
    for (int ks = 0; ks < 8; ++ks) {
        const int k0 = ks * 32;
        const bf16x8 a0 = *(const bf16x8*)(arow0 + k0);
        const bf16x8 a1 = *(const bf16x8*)(arow1 + k0);
        #pragma unroll
        for (int j = 0; j < 4; ++j) {
            const bf16x8 b = *(const bf16x8*)(brow0 + j * 16 * HDIM + k0);
            acc[0][j] = __builtin_amdgcn_mfma_f32_16x16x32_bf16(a0, b, acc[0][j], 0, 0, 0);
            acc[1][j] = __builtin_amdgcn_mfma_f32_16x16x32_bf16(a1, b, acc[1][j], 0, 0, 0);
        }
    }

    #pragma unroll
    for (int i = 0; i < 2; ++i) {
        #pragma unroll
        for (int j = 0; j < 4; ++j) {
            const int gn = n0 + 16 * j + lr;
            const float bv = bias[gn];
            #pragma unroll
            for (int q = 0; q < 4; ++q) {
                const int gm = mblk + 16 * i + lk * 4 + q;
                if (gm < M) {
                    float v = acc[i][j][q] + bv + agg[(size_t)gm * HDIM + gn];
                    if (RELU_BF) {
                        hb[(size_t)gm * HDIM + gn] = f2bf(fmaxf(v, 0.f));
                    } else {
                        outF[(size_t)gm * HDIM + gn] = v;
                    }
                }
            }
        }
    }
}

extern "C" void kernel_launch(void* const* d_in, const int* in_sizes, int n_in,
                              void* d_out, int out_size, void* d_ws, size_t ws_size,
                              hipStream_t stream) {
    const float* x    = (const float*)d_in[0];
    const int*   src  = (const int*)d_in[1];
    const int*   dst  = (const int*)d_in[2];
    const int*   et   = (const int*)d_in[3];
    const float* norm = (const float*)d_in[4];
    const float* w1   = (const float*)d_in[5];
    const float* lw1  = (const float*)d_in[6];
    const float* b1   = (const float*)d_in[7];
    const float* w2   = (const float*)d_in[8];
    const float* lw2  = (const float*)d_in[9];
    const float* b2   = (const float*)d_in[10];

    const int M = in_sizes[0] / HDIM;   // 20000
    const int E = in_sizes[1];          // 320000

    float* out = (float*)d_out;
    char*  ws  = (char*)d_ws;

    // ws layout (~23.6 MB)
    size_t off = 0;
    unsigned short* xb  = (unsigned short*)(ws + off); off += (size_t)M * HDIM * 2;
    unsigned short* h2b = (unsigned short*)(ws + off); off += (size_t)M * HDIM * 2;
    unsigned short* w1t = (unsigned short*)(ws + off); off += 65536 * 2;
    unsigned short* w2t = (unsigned short*)(ws + off); off += 65536 * 2;
    int* start = (int*)(ws + off);  off += (size_t)(M + 1) * 4; off = (off + 15) & ~15ull;
    int* cnt   = (int*)(ws + off);  off += (size_t)M * 4;       off = (off + 15) & ~15ull;
    int* deg   = (int*)(ws + off);  off += (size_t)M * 4;       off = (off + 15) & ~15ull;
    int2* epack = (int2*)(ws + off); off += (size_t)E * 8;
    (void)ws_size;

    // ---- preprocess ----
    convert_kernel<<<2048, 256, 0, stream>>>(x, xb, lw1, w1t, lw2, w2t, deg, M * HDIM, M);
    hist_kernel<<<512, 256, 0, stream>>>(dst, deg, E);
    scan_kernel<<<1, 1024, 0, stream>>>(deg, start, cnt, M);
    scatter_kernel<<<512, 256, 0, stream>>>(src, dst, et, norm, cnt, epack, E);

    const int nblk = (M + AWPB - 1) / AWPB;
    const int gblk = (M + 31) / 32;

    // Layer 1: agg1 -> out (scratch), h2b = bf16(relu(agg1 + b1 + xb@lw1))
    agg_kernel<<<nblk, 512, 0, stream>>>(xb, epack, start, w1, out, M);
    mfma_gemm<1><<<gblk, 256, 0, stream>>>(xb, w1t, b1, out, nullptr, h2b, M);

    // Layer 2: agg2 -> out, out = agg2 + b2 + h2b@lw2 (element-wise in-place)
    agg_kernel<<<nblk, 512, 0, stream>>>(h2b, epack, start, w2, out, M);
    mfma_gemm<0><<<gblk, 256, 0, stream>>>(h2b, w2t, b2, out, out, nullptr, M);
}

// Round 7
// 203.687 us; speedup vs baseline: 1.1758x; 1.1175x over previous
//
#include <hip/hip_runtime.h>

#define HDIM 256
#define NREL 16
#define NBLK 128
#define AWPB 8   // waves (nodes) per agg block

typedef __attribute__((ext_vector_type(8))) _Float16 f16x8;
typedef __attribute__((ext_vector_type(2))) _Float16 h2;
typedef __attribute__((ext_vector_type(4))) float f32x4;

__device__ __forceinline__ unsigned short f2h(float f) {
    return __builtin_bit_cast(unsigned short, (_Float16)f);
}

// ---------------- convert x->fp16, loop_w -> fp16 transposed, zero deg ----------------
__global__ void convert_kernel(const float* __restrict__ x, unsigned short* __restrict__ xh,
                               const float* __restrict__ lw1, unsigned short* __restrict__ w1t,
                               const float* __restrict__ lw2, unsigned short* __restrict__ w2t,
                               int* __restrict__ deg, int nx, int M) {
    const int total = nx + 131072 + M;
    for (int i = blockIdx.x * blockDim.x + threadIdx.x; i < total; i += gridDim.x * blockDim.x) {
        if (i < nx) {
            xh[i] = f2h(x[i]);
        } else if (i < nx + 65536) {
            int j = i - nx; int n = j >> 8, k = j & 255;
            w1t[j] = f2h(lw1[k * HDIM + n]);   // W^T[n][k]
        } else if (i < nx + 131072) {
            int j = i - nx - 65536; int n = j >> 8, k = j & 255;
            w2t[j] = f2h(lw2[k * HDIM + n]);
        } else {
            deg[i - nx - 131072] = 0;
        }
    }
}

// ---------------- counting-sort by dst ----------------
__global__ void hist_kernel(const int* __restrict__ dst, int* __restrict__ deg, int E) {
    for (int e = blockIdx.x * blockDim.x + threadIdx.x; e < E; e += gridDim.x * blockDim.x)
        atomicAdd(&deg[dst[e]], 1);
}

__global__ __launch_bounds__(1024) void scan_kernel(const int* __restrict__ deg,
                                                    int* __restrict__ start,
                                                    int* __restrict__ cnt, int N) {
    __shared__ int part[1024];
    const int t = threadIdx.x;
    const int CH = (N + 1023) >> 10;
    const int c0 = t * CH;
    int sum = 0;
    for (int i = 0; i < CH; ++i) { int idx = c0 + i; if (idx < N) sum += deg[idx]; }
    part[t] = sum;
    __syncthreads();
    for (int off = 1; off < 1024; off <<= 1) {
        int v = (t >= off) ? part[t - off] : 0;
        __syncthreads();
        part[t] += v;
        __syncthreads();
    }
    int run = (t > 0) ? part[t - 1] : 0;
    for (int i = 0; i < CH; ++i) {
        int idx = c0 + i;
        if (idx < N) { start[idx] = run; cnt[idx] = run; run += deg[idx]; }
    }
    if (t == 1023) start[N] = part[1023];
}

__global__ void scatter_kernel(const int* __restrict__ src, const int* __restrict__ dst,
                               const int* __restrict__ et, const float* __restrict__ norm,
                               int* __restrict__ cnt, int2* __restrict__ epack, int E) {
    for (int e = blockIdx.x * blockDim.x + threadIdx.x; e < E; e += gridDim.x * blockDim.x) {
        int d = dst[e];
        int pos = atomicAdd(&cnt[d], 1);
        epack[pos] = make_int2(src[e] * NREL + et[e], __float_as_int(norm[e]));
    }
}

// ---------------- per-edge micro-matmul: lane owns blocks b0..b0+3 (8 channels) ----------------
// xa: 4 uints = packed fp16 pairs (x[2b], x[2b+1]); w0/w1: packed (w[b,0,io], w[b,1,io])
__device__ __forceinline__ void accum8(float acc[8], uint4 xa, uint4 w0, uint4 w1, h2 nm2) {
    h2 xs0 = __builtin_bit_cast(h2, xa.x) * nm2;
    h2 xs1 = __builtin_bit_cast(h2, xa.y) * nm2;
    h2 xs2 = __builtin_bit_cast(h2, xa.z) * nm2;
    h2 xs3 = __builtin_bit_cast(h2, xa.w) * nm2;
    acc[0] = __builtin_amdgcn_fdot2(xs0, __builtin_bit_cast(h2, w0.x), acc[0], false);
    acc[1] = __builtin_amdgcn_fdot2(xs0, __builtin_bit_cast(h2, w1.x), acc[1], false);
    acc[2] = __builtin_amdgcn_fdot2(xs1, __builtin_bit_cast(h2, w0.y), acc[2], false);
    acc[3] = __builtin_amdgcn_fdot2(xs1, __builtin_bit_cast(h2, w1.y), acc[3], false);
    acc[4] = __builtin_amdgcn_fdot2(xs2, __builtin_bit_cast(h2, w0.z), acc[4], false);
    acc[5] = __builtin_amdgcn_fdot2(xs2, __builtin_bit_cast(h2, w1.z), acc[5], false);
    acc[6] = __builtin_amdgcn_fdot2(xs3, __builtin_bit_cast(h2, w0.w), acc[6], false);
    acc[7] = __builtin_amdgcn_fdot2(xs3, __builtin_bit_cast(h2, w1.w), acc[7], false);
}

// process 2 edges (one per half-wave) given int4 q = (e_even, n_even, e_odd, n_odd)
__device__ __forceinline__ void edge2(float acc[8], const unsigned short* __restrict__ xin,
                                      const unsigned int* wp, int4 q, int hl, int c2, int b0) {
    const int   e  = hl ? q.z : q.x;
    const float nm = __int_as_float(hl ? q.w : q.y);
    const _Float16 nh = (_Float16)nm;
    const h2 nm2 = {nh, nh};
    const uint4 xa = *(const uint4*)(xin + (size_t)(e >> 4) * HDIM + c2);
    const int r = e & (NREL - 1);
    const uint4 w0 = *(const uint4*)(wp + (r * 2 + 0) * NBLK + b0);
    const uint4 w1 = *(const uint4*)(wp + (r * 2 + 1) * NBLK + b0);
    accum8(acc, xa, w0, w1, nm2);
}

// ---------------- pull aggregation: wave-per-node, dual-edge ----------------
__global__ __launch_bounds__(512) void agg_kernel(
    const unsigned short* __restrict__ xin,  // fp16 [M,256]
    const int2* __restrict__ epack,
    const int* __restrict__ start,
    const float* __restrict__ w,             // (R,B,2,2) f32
    float* __restrict__ agg,
    int N)
{
    // packed fp16 weight pairs: wp[(r*2+io)*128 + b] = (h(w[r,b,0,io]), h(w[r,b,1,io]))
    __shared__ unsigned int wp[NREL * 2 * NBLK];   // 16 KB
    for (int j = threadIdx.x; j < NREL * 256; j += blockDim.x) {
        int r = j >> 8, t8 = j & 255, b = t8 >> 1, io = t8 & 1;
        float w0 = w[r * 512 + b * 4 + io];
        float w1 = w[r * 512 + b * 4 + 2 + io];
        wp[(r * 2 + io) * NBLK + b] = (unsigned)f2h(w0) | ((unsigned)f2h(w1) << 16);
    }
    __syncthreads();

    const int wv  = threadIdx.x >> 6;
    const int l   = threadIdx.x & 63;
    const int hl  = l >> 5;          // 0: even edge, 1: odd edge
    const int m32 = l & 31;
    const int c2  = m32 * 8;         // channel base (8 channels)
    const int b0  = m32 * 4;         // block base (4 blocks)

    for (int d = blockIdx.x * AWPB + wv; d < N; d += gridDim.x * AWPB) {
        const int s0 = start[d], s1 = start[d + 1];
        float acc[8] = {0.f, 0.f, 0.f, 0.f, 0.f, 0.f, 0.f, 0.f};
        int idx = s0;
        for (; idx + 8 <= s1; idx += 8) {
            const int4 q0 = *(const int4*)&epack[idx + 0];
            const int4 q1 = *(const int4*)&epack[idx + 2];
            const int4 q2 = *(const int4*)&epack[idx + 4];
            const int4 q3 = *(const int4*)&epack[idx + 6];
            edge2(acc, xin, wp, q0, hl, c2, b0);
            edge2(acc, xin, wp, q1, hl, c2, b0);
            edge2(acc, xin, wp, q2, hl, c2, b0);
            edge2(acc, xin, wp, q3, hl, c2, b0);
        }
        for (; idx + 2 <= s1; idx += 2) {
            const int4 q = *(const int4*)&epack[idx];
            edge2(acc, xin, wp, q, hl, c2, b0);
        }
        if (idx < s1) {
            const int2 p = epack[idx];
            const int4 q = make_int4(p.x, p.y, p.x, 0);   // odd half: nm=0
            edge2(acc, xin, wp, q, hl, c2, b0);
        }
        #pragma unroll
        for (int k = 0; k < 8; ++k) acc[k] += __shfl_xor(acc[k], 32);
        const float4 o = hl ? make_float4(acc[4], acc[5], acc[6], acc[7])
                            : make_float4(acc[0], acc[1], acc[2], acc[3]);
        *(float4*)(agg + (size_t)d * HDIM + c2 + 4 * hl) = o;
    }
}

// ---------------- MFMA self-loop GEMM: out = [relu](A @ W^T + bias + agg) ----------------
// Block = 256 thr = 4 waves; 32 m-rows x 256 n-cols (wave wv: n0 = 64*wv).
template <int RELU_H>
__global__ __launch_bounds__(256) void mfma_gemm(
    const unsigned short* __restrict__ A,     // [M,256] fp16
    const unsigned short* __restrict__ BT,    // [256,256] fp16, BT[n][k] = W[k][n]
    const float* __restrict__ bias,
    const float* __restrict__ agg,
    float* __restrict__ outF,
    unsigned short* __restrict__ hb,
    int M)
{
    const int wv = threadIdx.x >> 6;
    const int l  = threadIdx.x & 63;
    const int lr = l & 15;
    const int lk = l >> 4;
    const int mblk = blockIdx.x * 32;
    const int n0 = wv * 64;

    f32x4 acc[2][4] = {};

    const unsigned short* arow0 = A + (size_t)(mblk + lr) * HDIM + lk * 8;
    const unsigned short* arow1 = arow0 + 16 * HDIM;
    const unsigned short* brow0 = BT + (size_t)(n0 + lr) * HDIM + lk * 8;

    #pragma unroll
    for (int ks = 0; ks < 8; ++ks) {
        const int k0 = ks * 32;
        const f16x8 a0 = *(const f16x8*)(arow0 + k0);
        const f16x8 a1 = *(const f16x8*)(arow1 + k0);
        #pragma unroll
        for (int j = 0; j < 4; ++j) {
            const f16x8 b = *(const f16x8*)(brow0 + j * 16 * HDIM + k0);
            acc[0][j] = __builtin_amdgcn_mfma_f32_16x16x32_f16(a0, b, acc[0][j], 0, 0, 0);
            acc[1][j] = __builtin_amdgcn_mfma_f32_16x16x32_f16(a1, b, acc[1][j], 0, 0, 0);
        }
    }

    #pragma unroll
    for (int i = 0; i < 2; ++i) {
        #pragma unroll
        for (int j = 0; j < 4; ++j) {
            const int gn = n0 + 16 * j + lr;
            const float bv = bias[gn];
            #pragma unroll
            for (int q = 0; q < 4; ++q) {
                const int gm = mblk + 16 * i + lk * 4 + q;
                if (gm < M) {
                    float v = acc[i][j][q] + bv + agg[(size_t)gm * HDIM + gn];
                    if (RELU_H) {
                        hb[(size_t)gm * HDIM + gn] = f2h(fmaxf(v, 0.f));
                    } else {
                        outF[(size_t)gm * HDIM + gn] = v;
                    }
                }
            }
        }
    }
}

extern "C" void kernel_launch(void* const* d_in, const int* in_sizes, int n_in,
                              void* d_out, int out_size, void* d_ws, size_t ws_size,
                              hipStream_t stream) {
    const float* x    = (const float*)d_in[0];
    const int*   src  = (const int*)d_in[1];
    const int*   dst  = (const int*)d_in[2];
    const int*   et   = (const int*)d_in[3];
    const float* norm = (const float*)d_in[4];
    const float* w1   = (const float*)d_in[5];
    const float* lw1  = (const float*)d_in[6];
    const float* b1   = (const float*)d_in[7];
    const float* w2   = (const float*)d_in[8];
    const float* lw2  = (const float*)d_in[9];
    const float* b2   = (const float*)d_in[10];

    const int M = in_sizes[0] / HDIM;   // 20000
    const int E = in_sizes[1];          // 320000

    float* out = (float*)d_out;
    char*  ws  = (char*)d_ws;

    // ws layout (~23.6 MB)
    size_t off = 0;
    unsigned short* xh  = (unsigned short*)(ws + off); off += (size_t)M * HDIM * 2;
    unsigned short* h2  = (unsigned short*)(ws + off); off += (size_t)M * HDIM * 2;
    unsigned short* w1t = (unsigned short*)(ws + off); off += 65536 * 2;
    unsigned short* w2t = (unsigned short*)(ws + off); off += 65536 * 2;
    int* start = (int*)(ws + off);  off += (size_t)(M + 1) * 4; off = (off + 15) & ~15ull;
    int* cnt   = (int*)(ws + off);  off += (size_t)M * 4;       off = (off + 15) & ~15ull;
    int* deg   = (int*)(ws + off);  off += (size_t)M * 4;       off = (off + 15) & ~15ull;
    int2* epack = (int2*)(ws + off); off += (size_t)E * 8;
    (void)ws_size;

    // ---- preprocess ----
    convert_kernel<<<2048, 256, 0, stream>>>(x, xh, lw1, w1t, lw2, w2t, deg, M * HDIM, M);
    hist_kernel<<<512, 256, 0, stream>>>(dst, deg, E);
    scan_kernel<<<1, 1024, 0, stream>>>(deg, start, cnt, M);
    scatter_kernel<<<512, 256, 0, stream>>>(src, dst, et, norm, cnt, epack, E);

    const int nblk = (M + AWPB - 1) / AWPB;
    const int gblk = (M + 31) / 32;

    // Layer 1: agg1 -> out (scratch), h2 = fp16(relu(agg1 + b1 + xh@lw1))
    agg_kernel<<<nblk, 512, 0, stream>>>(xh, epack, start, w1, out, M);
    mfma_gemm<1><<<gblk, 256, 0, stream>>>(xh, w1t, b1, out, nullptr, h2, M);

    // Layer 2: agg2 -> out, out = agg2 + b2 + h2@lw2 (element-wise in-place)
    agg_kernel<<<nblk, 512, 0, stream>>>(h2, epack, start, w2, out, M);
    mfma_gemm<0><<<gblk, 256, 0, stream>>>(h2, w2t, b2, out, out, nullptr, M);
}

// Round 8
// 203.326 us; speedup vs baseline: 1.1779x; 1.0018x over previous
//
#include <hip/hip_runtime.h>

#define HDIM 256
#define NREL 16
#define NBLK 128
#define AWPB 8   // waves (nodes) per agg block

typedef __attribute__((ext_vector_type(8))) _Float16 f16x8;
typedef __attribute__((ext_vector_type(2))) _Float16 h2;
typedef __attribute__((ext_vector_type(4))) float f32x4;

__device__ __forceinline__ unsigned short f2h(float f) {
    return __builtin_bit_cast(unsigned short, (_Float16)f);
}

// ---------------- convert x->fp16, loop_w -> fp16 transposed, zero deg ----------------
__global__ void convert_kernel(const float* __restrict__ x, unsigned short* __restrict__ xh,
                               const float* __restrict__ lw1, unsigned short* __restrict__ w1t,
                               const float* __restrict__ lw2, unsigned short* __restrict__ w2t,
                               int* __restrict__ deg, int nx, int M) {
    const int total = nx + 131072 + M;
    for (int i = blockIdx.x * blockDim.x + threadIdx.x; i < total; i += gridDim.x * blockDim.x) {
        if (i < nx) {
            xh[i] = f2h(x[i]);
        } else if (i < nx + 65536) {
            int j = i - nx; int n = j >> 8, k = j & 255;
            w1t[j] = f2h(lw1[k * HDIM + n]);   // W^T[n][k]
        } else if (i < nx + 131072) {
            int j = i - nx - 65536; int n = j >> 8, k = j & 255;
            w2t[j] = f2h(lw2[k * HDIM + n]);
        } else {
            deg[i - nx - 131072] = 0;
        }
    }
}

// ---------------- counting-sort by dst ----------------
__global__ void hist_kernel(const int* __restrict__ dst, int* __restrict__ deg, int E) {
    for (int e = blockIdx.x * blockDim.x + threadIdx.x; e < E; e += gridDim.x * blockDim.x)
        atomicAdd(&deg[dst[e]], 1);
}

__global__ __launch_bounds__(1024) void scan_kernel(const int* __restrict__ deg,
                                                    int* __restrict__ start,
                                                    int* __restrict__ cnt, int N) {
    __shared__ int part[1024];
    const int t = threadIdx.x;
    const int CH = (N + 1023) >> 10;
    const int c0 = t * CH;
    int sum = 0;
    for (int i = 0; i < CH; ++i) { int idx = c0 + i; if (idx < N) sum += deg[idx]; }
    part[t] = sum;
    __syncthreads();
    for (int off = 1; off < 1024; off <<= 1) {
        int v = (t >= off) ? part[t - off] : 0;
        __syncthreads();
        part[t] += v;
        __syncthreads();
    }
    int run = (t > 0) ? part[t - 1] : 0;
    for (int i = 0; i < CH; ++i) {
        int idx = c0 + i;
        if (idx < N) { start[idx] = run; cnt[idx] = run; run += deg[idx]; }
    }
    if (t == 1023) start[N] = part[1023];
}

__global__ void scatter_kernel(const int* __restrict__ src, const int* __restrict__ dst,
                               const int* __restrict__ et, const float* __restrict__ norm,
                               int* __restrict__ cnt, int2* __restrict__ epack, int E) {
    for (int e = blockIdx.x * blockDim.x + threadIdx.x; e < E; e += gridDim.x * blockDim.x) {
        int d = dst[e];
        int pos = atomicAdd(&cnt[d], 1);
        epack[pos] = make_int2(src[e] * NREL + et[e], __float_as_int(norm[e]));
    }
}

// ---------------- per-edge micro-matmul: lane owns blocks b0..b0+3 (8 channels) ----------------
// xa: 4 uints = packed fp16 pairs (x[2b], x[2b+1]); w0/w1: packed (w[b,0,io], w[b,1,io])
__device__ __forceinline__ void accum8(float acc[8], uint4 xa, uint4 w0, uint4 w1, h2 nm2) {
    h2 xs0 = __builtin_bit_cast(h2, xa.x) * nm2;
    h2 xs1 = __builtin_bit_cast(h2, xa.y) * nm2;
    h2 xs2 = __builtin_bit_cast(h2, xa.z) * nm2;
    h2 xs3 = __builtin_bit_cast(h2, xa.w) * nm2;
    acc[0] = __builtin_amdgcn_fdot2(xs0, __builtin_bit_cast(h2, w0.x), acc[0], false);
    acc[1] = __builtin_amdgcn_fdot2(xs0, __builtin_bit_cast(h2, w1.x), acc[1], false);
    acc[2] = __builtin_amdgcn_fdot2(xs1, __builtin_bit_cast(h2, w0.y), acc[2], false);
    acc[3] = __builtin_amdgcn_fdot2(xs1, __builtin_bit_cast(h2, w1.y), acc[3], false);
    acc[4] = __builtin_amdgcn_fdot2(xs2, __builtin_bit_cast(h2, w0.z), acc[4], false);
    acc[5] = __builtin_amdgcn_fdot2(xs2, __builtin_bit_cast(h2, w1.z), acc[5], false);
    acc[6] = __builtin_amdgcn_fdot2(xs3, __builtin_bit_cast(h2, w0.w), acc[6], false);
    acc[7] = __builtin_amdgcn_fdot2(xs3, __builtin_bit_cast(h2, w1.w), acc[7], false);
}

// process 2 edges (one per half-wave) given int4 q = (e_even, n_even, e_odd, n_odd)
__device__ __forceinline__ void edge2(float acc[8], const unsigned short* __restrict__ xin,
                                      const unsigned int* wp, int4 q, int hl, int c2, int b0) {
    const int   e  = hl ? q.z : q.x;
    const float nm = __int_as_float(hl ? q.w : q.y);
    const _Float16 nh = (_Float16)nm;
    const h2 nm2 = {nh, nh};
    const uint4 xa = *(const uint4*)(xin + (size_t)(e >> 4) * HDIM + c2);
    const int r = e & (NREL - 1);
    const uint4 w0 = *(const uint4*)(wp + (r * 2 + 0) * NBLK + b0);
    const uint4 w1 = *(const uint4*)(wp + (r * 2 + 1) * NBLK + b0);
    accum8(acc, xa, w0, w1, nm2);
}

// ---------------- pull aggregation: wave-per-node, dual-edge ----------------
__global__ __launch_bounds__(512) void agg_kernel(
    const unsigned short* __restrict__ xin,  // fp16 [M,256]
    const int2* __restrict__ epack,
    const int* __restrict__ start,
    const float* __restrict__ w,             // (R,B,2,2) f32
    float* __restrict__ agg,
    int N)
{
    // packed fp16 weight pairs: wp[(r*2+io)*128 + b] = (h(w[r,b,0,io]), h(w[r,b,1,io]))
    __shared__ unsigned int wp[NREL * 2 * NBLK];   // 16 KB
    for (int j = threadIdx.x; j < NREL * 256; j += blockDim.x) {
        int r = j >> 8, t8 = j & 255, b = t8 >> 1, io = t8 & 1;
        float w0 = w[r * 512 + b * 4 + io];
        float w1 = w[r * 512 + b * 4 + 2 + io];
        wp[(r * 2 + io) * NBLK + b] = (unsigned)f2h(w0) | ((unsigned)f2h(w1) << 16);
    }
    __syncthreads();

    const int wv  = threadIdx.x >> 6;
    const int l   = threadIdx.x & 63;
    const int hl  = l >> 5;          // 0: even edge, 1: odd edge
    const int m32 = l & 31;
    const int c2  = m32 * 8;         // channel base (8 channels)
    const int b0  = m32 * 4;         // block base (4 blocks)

    for (int d = blockIdx.x * AWPB + wv; d < N; d += gridDim.x * AWPB) {
        const int s0 = start[d], s1 = start[d + 1];
        float acc[8] = {0.f, 0.f, 0.f, 0.f, 0.f, 0.f, 0.f, 0.f};
        int idx = s0;
        for (; idx + 8 <= s1; idx += 8) {
            const int4 q0 = *(const int4*)&epack[idx + 0];
            const int4 q1 = *(const int4*)&epack[idx + 2];
            const int4 q2 = *(const int4*)&epack[idx + 4];
            const int4 q3 = *(const int4*)&epack[idx + 6];
            edge2(acc, xin, wp, q0, hl, c2, b0);
            edge2(acc, xin, wp, q1, hl, c2, b0);
            edge2(acc, xin, wp, q2, hl, c2, b0);
            edge2(acc, xin, wp, q3, hl, c2, b0);
        }
        for (; idx + 2 <= s1; idx += 2) {
            const int4 q = *(const int4*)&epack[idx];
            edge2(acc, xin, wp, q, hl, c2, b0);
        }
        if (idx < s1) {
            const int2 p = epack[idx];
            const int4 q = make_int4(p.x, p.y, p.x, 0);   // odd half: nm=0
            edge2(acc, xin, wp, q, hl, c2, b0);
        }
        #pragma unroll
        for (int k = 0; k < 8; ++k) acc[k] += __shfl_xor(acc[k], 32);
        const float4 o = hl ? make_float4(acc[4], acc[5], acc[6], acc[7])
                            : make_float4(acc[0], acc[1], acc[2], acc[3]);
        *(float4*)(agg + (size_t)d * HDIM + c2 + 4 * hl) = o;
    }
}

// ---------------- MFMA self-loop GEMM: out = [relu](A @ W^T + bias + agg) ----------------
// Block = 256 thr = 4 waves; 32 m-rows x 256 n-cols (wave wv: n0 = 64*wv).
template <int RELU_H>
__global__ __launch_bounds__(256) void mfma_gemm(
    const unsigned short* __restrict__ A,     // [M,256] fp16
    const unsigned short* __restrict__ BT,    // [256,256] fp16, BT[n][k] = W[k][n]
    const float* __restrict__ bias,
    const float* __restrict__ agg,
    float* __restrict__ outF,
    unsigned short* __restrict__ hb,
    int M)
{
    const int wv = threadIdx.x >> 6;
    const int l  = threadIdx.x & 63;
    const int lr = l & 15;
    const int lk = l >> 4;
    const int mblk = blockIdx.x * 32;
    const int n0 = wv * 64;

    f32x4 acc[2][4] = {};

    const unsigned short* arow0 = A + (size_t)(mblk + lr) * HDIM + lk * 8;
    const unsigned short* arow1 = arow0 + 16 * HDIM;
    const unsigned short* brow0 = BT + (size_t)(n0 + lr) * HDIM + lk * 8;

    #pragma unroll
    for (int ks = 0; ks < 8; ++ks) {
        const int k0 = ks * 32;
        const f16x8 a0 = *(const f16x8*)(arow0 + k0);
        const f16x8 a1 = *(const f16x8*)(arow1 + k0);
        #pragma unroll
        for (int j = 0; j < 4; ++j) {
            const f16x8 b = *(const f16x8*)(brow0 + j * 16 * HDIM + k0);
            acc[0][j] = __builtin_amdgcn_mfma_f32_16x16x32_f16(a0, b, acc[0][j], 0, 0, 0);
            acc[1][j] = __builtin_amdgcn_mfma_f32_16x16x32_f16(a1, b, acc[1][j], 0, 0, 0);
        }
    }

    #pragma unroll
    for (int i = 0; i < 2; ++i) {
        #pragma unroll
        for (int j = 0; j < 4; ++j) {
            const int gn = n0 + 16 * j + lr;
            const float bv = bias[gn];
            #pragma unroll
            for (int q = 0; q < 4; ++q) {
                const int gm = mblk + 16 * i + lk * 4 + q;
                if (gm < M) {
                    float v = acc[i][j][q] + bv + agg[(size_t)gm * HDIM + gn];
                    if (RELU_H) {
                        hb[(size_t)gm * HDIM + gn] = f2h(fmaxf(v, 0.f));
                    } else {
                        outF[(size_t)gm * HDIM + gn] = v;
                    }
                }
            }
        }
    }
}

extern "C" void kernel_launch(void* const* d_in, const int* in_sizes, int n_in,
                              void* d_out, int out_size, void* d_ws, size_t ws_size,
                              hipStream_t stream) {
    const float* x    = (const float*)d_in[0];
    const int*   src  = (const int*)d_in[1];
    const int*   dst  = (const int*)d_in[2];
    const int*   et   = (const int*)d_in[3];
    const float* norm = (const float*)d_in[4];
    const float* w1   = (const float*)d_in[5];
    const float* lw1  = (const float*)d_in[6];
    const float* b1   = (const float*)d_in[7];
    const float* w2   = (const float*)d_in[8];
    const float* lw2  = (const float*)d_in[9];
    const float* b2   = (const float*)d_in[10];

    const int M = in_sizes[0] / HDIM;   // 20000
    const int E = in_sizes[1];          // 320000

    float* out = (float*)d_out;
    char*  ws  = (char*)d_ws;

    // ws layout (~23.6 MB)
    size_t off = 0;
    unsigned short* xh  = (unsigned short*)(ws + off); off += (size_t)M * HDIM * 2;
    unsigned short* h2  = (unsigned short*)(ws + off); off += (size_t)M * HDIM * 2;
    unsigned short* w1t = (unsigned short*)(ws + off); off += 65536 * 2;
    unsigned short* w2t = (unsigned short*)(ws + off); off += 65536 * 2;
    int* start = (int*)(ws + off);  off += (size_t)(M + 1) * 4; off = (off + 15) & ~15ull;
    int* cnt   = (int*)(ws + off);  off += (size_t)M * 4;       off = (off + 15) & ~15ull;
    int* deg   = (int*)(ws + off);  off += (size_t)M * 4;       off = (off + 15) & ~15ull;
    int2* epack = (int2*)(ws + off); off += (size_t)E * 8;
    (void)ws_size;

    // ---- preprocess ----
    convert_kernel<<<2048, 256, 0, stream>>>(x, xh, lw1, w1t, lw2, w2t, deg, M * HDIM, M);
    hist_kernel<<<512, 256, 0, stream>>>(dst, deg, E);
    scan_kernel<<<1, 1024, 0, stream>>>(deg, start, cnt, M);
    scatter_kernel<<<512, 256, 0, stream>>>(src, dst, et, norm, cnt, epack, E);

    const int nblk = (M + AWPB - 1) / AWPB;
    const int gblk = (M + 31) / 32;

    // Layer 1: agg1 -> out (scratch), h2 = fp16(relu(agg1 + b1 + xh@lw1))
    agg_kernel<<<nblk, 512, 0, stream>>>(xh, epack, start, w1, out, M);
    mfma_gemm<1><<<gblk, 256, 0, stream>>>(xh, w1t, b1, out, nullptr, h2, M);

    // Layer 2: agg2 -> out, out = agg2 + b2 + h2@lw2 (element-wise in-place)
    agg_kernel<<<nblk, 512, 0, stream>>>(h2, epack, start, w2, out, M);
    mfma_gemm<0><<<gblk, 256, 0, stream>>>(h2, w2t, b2, out, out, nullptr, M);
}

// Round 9
// 201.804 us; speedup vs baseline: 1.1868x; 1.0075x over previous
//
#include <hip/hip_runtime.h>

#define HDIM 256
#define NREL 16
#define NBLK 128
#define AWPB 8   // waves per agg block (each wave = 2 nodes)

typedef __attribute__((ext_vector_type(8))) _Float16 f16x8;
typedef __attribute__((ext_vector_type(2))) _Float16 h2;
typedef __attribute__((ext_vector_type(4))) float f32x4;

__device__ __forceinline__ unsigned short f2h(float f) {
    return __builtin_bit_cast(unsigned short, (_Float16)f);
}
__device__ __forceinline__ float h2f(unsigned short s) {
    return (float)__builtin_bit_cast(_Float16, s);
}

// ---------------- convert x->fp16, loop_w -> fp16 transposed, zero deg ----------------
__global__ void convert_kernel(const float* __restrict__ x, unsigned short* __restrict__ xh,
                               const float* __restrict__ lw1, unsigned short* __restrict__ w1t,
                               const float* __restrict__ lw2, unsigned short* __restrict__ w2t,
                               int* __restrict__ deg, int nx, int M) {
    const int total = nx + 131072 + M;
    for (int i = blockIdx.x * blockDim.x + threadIdx.x; i < total; i += gridDim.x * blockDim.x) {
        if (i < nx) {
            xh[i] = f2h(x[i]);
        } else if (i < nx + 65536) {
            int j = i - nx; int n = j >> 8, k = j & 255;
            w1t[j] = f2h(lw1[k * HDIM + n]);   // W^T[n][k]
        } else if (i < nx + 131072) {
            int j = i - nx - 65536; int n = j >> 8, k = j & 255;
            w2t[j] = f2h(lw2[k * HDIM + n]);
        } else {
            deg[i - nx - 131072] = 0;
        }
    }
}

// ---------------- counting-sort by dst ----------------
__global__ void hist_kernel(const int* __restrict__ dst, int* __restrict__ deg, int E) {
    for (int e = blockIdx.x * blockDim.x + threadIdx.x; e < E; e += gridDim.x * blockDim.x)
        atomicAdd(&deg[dst[e]], 1);
}

__global__ __launch_bounds__(1024) void scan_kernel(const int* __restrict__ deg,
                                                    int* __restrict__ start,
                                                    int* __restrict__ cnt, int N) {
    __shared__ int part[1024];
    const int t = threadIdx.x;
    const int CH = (N + 1023) >> 10;
    const int c0 = t * CH;
    int sum = 0;
    for (int i = 0; i < CH; ++i) { int idx = c0 + i; if (idx < N) sum += deg[idx]; }
    part[t] = sum;
    __syncthreads();
    for (int off = 1; off < 1024; off <<= 1) {
        int v = (t >= off) ? part[t - off] : 0;
        __syncthreads();
        part[t] += v;
        __syncthreads();
    }
    int run = (t > 0) ? part[t - 1] : 0;
    for (int i = 0; i < CH; ++i) {
        int idx = c0 + i;
        if (idx < N) { start[idx] = run; cnt[idx] = run; run += deg[idx]; }
    }
    if (t == 1023) start[N] = part[1023];
}

__global__ void scatter_kernel(const int* __restrict__ src, const int* __restrict__ dst,
                               const int* __restrict__ et, const float* __restrict__ norm,
                               int* __restrict__ cnt, int2* __restrict__ epack, int E) {
    for (int e = blockIdx.x * blockDim.x + threadIdx.x; e < E; e += gridDim.x * blockDim.x) {
        int d = dst[e];
        int pos = atomicAdd(&cnt[d], 1);
        epack[pos] = make_int2(src[e] * NREL + et[e], __float_as_int(norm[e]));
    }
}

// ---------------- per-edge micro-matmul: lane owns blocks b0..b0+3 (8 channels) ----------------
__device__ __forceinline__ void accum8(float acc[8], uint4 xa, uint4 w0, uint4 w1, h2 nm2) {
    h2 xs0 = __builtin_bit_cast(h2, xa.x) * nm2;
    h2 xs1 = __builtin_bit_cast(h2, xa.y) * nm2;
    h2 xs2 = __builtin_bit_cast(h2, xa.z) * nm2;
    h2 xs3 = __builtin_bit_cast(h2, xa.w) * nm2;
    acc[0] = __builtin_amdgcn_fdot2(xs0, __builtin_bit_cast(h2, w0.x), acc[0], false);
    acc[1] = __builtin_amdgcn_fdot2(xs0, __builtin_bit_cast(h2, w1.x), acc[1], false);
    acc[2] = __builtin_amdgcn_fdot2(xs1, __builtin_bit_cast(h2, w0.y), acc[2], false);
    acc[3] = __builtin_amdgcn_fdot2(xs1, __builtin_bit_cast(h2, w1.y), acc[3], false);
    acc[4] = __builtin_amdgcn_fdot2(xs2, __builtin_bit_cast(h2, w0.z), acc[4], false);
    acc[5] = __builtin_amdgcn_fdot2(xs2, __builtin_bit_cast(h2, w1.z), acc[5], false);
    acc[6] = __builtin_amdgcn_fdot2(xs3, __builtin_bit_cast(h2, w0.w), acc[6], false);
    acc[7] = __builtin_amdgcn_fdot2(xs3, __builtin_bit_cast(h2, w1.w), acc[7], false);
}

// process 2 edges (one per half-wave): int4 q = (e_even, n_even, e_odd, n_odd)
__device__ __forceinline__ void edge2(float acc[8], const unsigned short* __restrict__ xin,
                                      const unsigned int* wp, int4 q, int hl, int c2, int b0) {
    const int   e  = hl ? q.z : q.x;
    const float nm = __int_as_float(hl ? q.w : q.y);
    const _Float16 nh = (_Float16)nm;
    const h2 nm2 = {nh, nh};
    const uint4 xa = *(const uint4*)(xin + (size_t)(e >> 4) * HDIM + c2);
    const int r = e & (NREL - 1);
    const uint4 w0 = *(const uint4*)(wp + (r * 2 + 0) * NBLK + b0);
    const uint4 w1 = *(const uint4*)(wp + (r * 2 + 1) * NBLK + b0);
    accum8(acc, xa, w0, w1, nm2);
}

// ---------------- pull aggregation: 2 nodes per wave, interleaved streams, fp16 out ----------------
__global__ __launch_bounds__(512, 4) void agg_kernel(
    const unsigned short* __restrict__ xin,  // fp16 [M,256]
    const int2* __restrict__ epack,
    const int* __restrict__ start,
    const float* __restrict__ w,             // (R,B,2,2) f32
    unsigned short* __restrict__ aggH,       // fp16 [M,256] out
    int N)
{
    __shared__ unsigned int wp[NREL * 2 * NBLK];   // 16 KB packed fp16 weight pairs
    for (int j = threadIdx.x; j < NREL * 256; j += blockDim.x) {
        int r = j >> 8, t8 = j & 255, b = t8 >> 1, io = t8 & 1;
        float w0 = w[r * 512 + b * 4 + io];
        float w1 = w[r * 512 + b * 4 + 2 + io];
        wp[(r * 2 + io) * NBLK + b] = (unsigned)f2h(w0) | ((unsigned)f2h(w1) << 16);
    }
    __syncthreads();

    const int wv  = threadIdx.x >> 6;
    const int l   = threadIdx.x & 63;
    const int hl  = l >> 5;
    const int m32 = l & 31;
    const int c2  = m32 * 8;
    const int b0  = m32 * 4;

    const int pair = blockIdx.x * AWPB + wv;
    const int dA = pair * 2;
    if (dA >= N) return;
    const int dB = dA + 1;
    const bool hasB = (dB < N);

    int iA = start[dA];
    const int eA = start[dA + 1];
    int iB = hasB ? start[dB] : 0;
    const int eB = hasB ? start[dB + 1] : 0;

    float accA[8] = {0.f,0.f,0.f,0.f,0.f,0.f,0.f,0.f};
    float accB[8] = {0.f,0.f,0.f,0.f,0.f,0.f,0.f,0.f};

    // interleaved main loop: 4 edges of A + 4 of B per iter (4 independent gathers in flight)
    while (iA + 4 <= eA && iB + 4 <= eB) {
        const int4 qA0 = *(const int4*)&epack[iA + 0];
        const int4 qA1 = *(const int4*)&epack[iA + 2];
        const int4 qB0 = *(const int4*)&epack[iB + 0];
        const int4 qB1 = *(const int4*)&epack[iB + 2];
        edge2(accA, xin, wp, qA0, hl, c2, b0);
        edge2(accB, xin, wp, qB0, hl, c2, b0);
        edge2(accA, xin, wp, qA1, hl, c2, b0);
        edge2(accB, xin, wp, qB1, hl, c2, b0);
        iA += 4; iB += 4;
    }
    // drain A
    for (; iA + 8 <= eA; iA += 8) {
        const int4 q0 = *(const int4*)&epack[iA + 0];
        const int4 q1 = *(const int4*)&epack[iA + 2];
        const int4 q2 = *(const int4*)&epack[iA + 4];
        const int4 q3 = *(const int4*)&epack[iA + 6];
        edge2(accA, xin, wp, q0, hl, c2, b0);
        edge2(accA, xin, wp, q1, hl, c2, b0);
        edge2(accA, xin, wp, q2, hl, c2, b0);
        edge2(accA, xin, wp, q3, hl, c2, b0);
    }
    for (; iA + 2 <= eA; iA += 2) {
        const int4 q = *(const int4*)&epack[iA];
        edge2(accA, xin, wp, q, hl, c2, b0);
    }
    if (iA < eA) {
        const int2 p = epack[iA];
        edge2(accA, xin, wp, make_int4(p.x, p.y, p.x, 0), hl, c2, b0);
    }
    // drain B
    for (; iB + 8 <= eB; iB += 8) {
        const int4 q0 = *(const int4*)&epack[iB + 0];
        const int4 q1 = *(const int4*)&epack[iB + 2];
        const int4 q2 = *(const int4*)&epack[iB + 4];
        const int4 q3 = *(const int4*)&epack[iB + 6];
        edge2(accB, xin, wp, q0, hl, c2, b0);
        edge2(accB, xin, wp, q1, hl, c2, b0);
        edge2(accB, xin, wp, q2, hl, c2, b0);
        edge2(accB, xin, wp, q3, hl, c2, b0);
    }
    for (; iB + 2 <= eB; iB += 2) {
        const int4 q = *(const int4*)&epack[iB];
        edge2(accB, xin, wp, q, hl, c2, b0);
    }
    if (iB < eB) {
        const int2 p = epack[iB];
        edge2(accB, xin, wp, make_int4(p.x, p.y, p.x, 0), hl, c2, b0);
    }

    #pragma unroll
    for (int k = 0; k < 8; ++k) {
        accA[k] += __shfl_xor(accA[k], 32);
        accB[k] += __shfl_xor(accB[k], 32);
    }
    const int o = 4 * hl;
    ushort4 sA;
    sA.x = f2h(accA[o + 0]); sA.y = f2h(accA[o + 1]);
    sA.z = f2h(accA[o + 2]); sA.w = f2h(accA[o + 3]);
    *(ushort4*)(aggH + (size_t)dA * HDIM + c2 + o) = sA;
    if (hasB) {
        ushort4 sB;
        sB.x = f2h(accB[o + 0]); sB.y = f2h(accB[o + 1]);
        sB.z = f2h(accB[o + 2]); sB.w = f2h(accB[o + 3]);
        *(ushort4*)(aggH + (size_t)dB * HDIM + c2 + o) = sB;
    }
}

// ---------------- MFMA self-loop GEMM: out = [relu](A @ W^T + bias + aggH) ----------------
// Block = 256 thr = 4 waves; 32 m-rows x 256 n-cols (wave wv: n0 = 64*wv).
// RELU_H=1: hb[gm][gn] = fp16(relu(v)); hb MAY equal aggH (same-thread same-slot
//           read-before-write, element-wise — safe). RELU_H=0: outF[gm][gn] = v.
template <int RELU_H>
__global__ __launch_bounds__(256) void mfma_gemm(
    const unsigned short* __restrict__ A,     // [M,256] fp16
    const unsigned short* __restrict__ BT,    // [256,256] fp16, BT[n][k] = W[k][n]
    const float* __restrict__ bias,
    const unsigned short* aggH,               // fp16 agg (no restrict: may alias hb)
    float* __restrict__ outF,
    unsigned short* hb,
    int M)
{
    const int wv = threadIdx.x >> 6;
    const int l  = threadIdx.x & 63;
    const int lr = l & 15;
    const int lk = l >> 4;
    const int mblk = blockIdx.x * 32;
    const int n0 = wv * 64;

    f32x4 acc[2][4] = {};

    const unsigned short* arow0 = A + (size_t)(mblk + lr) * HDIM + lk * 8;
    const unsigned short* arow1 = arow0 + 16 * HDIM;
    const unsigned short* brow0 = BT + (size_t)(n0 + lr) * HDIM + lk * 8;

    #pragma unroll
    for (int ks = 0; ks < 8; ++ks) {
        const int k0 = ks * 32;
        const f16x8 a0 = *(const f16x8*)(arow0 + k0);
        const f16x8 a1 = *(const f16x8*)(arow1 + k0);
        #pragma unroll
        for (int j = 0; j < 4; ++j) {
            const f16x8 b = *(const f16x8*)(brow0 + j * 16 * HDIM + k0);
            acc[0][j] = __builtin_amdgcn_mfma_f32_16x16x32_f16(a0, b, acc[0][j], 0, 0, 0);
            acc[1][j] = __builtin_amdgcn_mfma_f32_16x16x32_f16(a1, b, acc[1][j], 0, 0, 0);
        }
    }

    #pragma unroll
    for (int i = 0; i < 2; ++i) {
        #pragma unroll
        for (int j = 0; j < 4; ++j) {
            const int gn = n0 + 16 * j + lr;
            const float bv = bias[gn];
            #pragma unroll
            for (int q = 0; q < 4; ++q) {
                const int gm = mblk + 16 * i + lk * 4 + q;
                if (gm < M) {
                    float v = acc[i][j][q] + bv + h2f(aggH[(size_t)gm * HDIM + gn]);
                    if (RELU_H) {
                        hb[(size_t)gm * HDIM + gn] = f2h(fmaxf(v, 0.f));
                    } else {
                        outF[(size_t)gm * HDIM + gn] = v;
                    }
                }
            }
        }
    }
}

extern "C" void kernel_launch(void* const* d_in, const int* in_sizes, int n_in,
                              void* d_out, int out_size, void* d_ws, size_t ws_size,
                              hipStream_t stream) {
    const float* x    = (const float*)d_in[0];
    const int*   src  = (const int*)d_in[1];
    const int*   dst  = (const int*)d_in[2];
    const int*   et   = (const int*)d_in[3];
    const float* norm = (const float*)d_in[4];
    const float* w1   = (const float*)d_in[5];
    const float* lw1  = (const float*)d_in[6];
    const float* b1   = (const float*)d_in[7];
    const float* w2   = (const float*)d_in[8];
    const float* lw2  = (const float*)d_in[9];
    const float* b2   = (const float*)d_in[10];

    const int M = in_sizes[0] / HDIM;   // 20000
    const int E = in_sizes[1];          // 320000

    float* out = (float*)d_out;
    char*  ws  = (char*)d_ws;

    // ws layout (~23.2 MB). Buffer lifetimes:
    //   xh: layer-1 features; dead after gemm1 -> reused as aggH(L2) by agg2.
    //   hbuf: aggH(L1) written by agg1; gemm1 reads aggH elem + writes h fp16 to SAME slot.
    size_t off = 0;
    unsigned short* xh   = (unsigned short*)(ws + off); off += (size_t)M * HDIM * 2;
    unsigned short* hbuf = (unsigned short*)(ws + off); off += (size_t)M * HDIM * 2;
    unsigned short* w1t  = (unsigned short*)(ws + off); off += 65536 * 2;
    unsigned short* w2t  = (unsigned short*)(ws + off); off += 65536 * 2;
    int* start = (int*)(ws + off);  off += (size_t)(M + 1) * 4; off = (off + 15) & ~15ull;
    int* cnt   = (int*)(ws + off);  off += (size_t)M * 4;       off = (off + 15) & ~15ull;
    int* deg   = (int*)(ws + off);  off += (size_t)M * 4;       off = (off + 15) & ~15ull;
    int2* epack = (int2*)(ws + off); off += (size_t)E * 8;
    (void)ws_size;

    // ---- preprocess ----
    convert_kernel<<<2048, 256, 0, stream>>>(x, xh, lw1, w1t, lw2, w2t, deg, M * HDIM, M);
    hist_kernel<<<512, 256, 0, stream>>>(dst, deg, E);
    scan_kernel<<<1, 1024, 0, stream>>>(deg, start, cnt, M);
    scatter_kernel<<<512, 256, 0, stream>>>(src, dst, et, norm, cnt, epack, E);

    const int npair = (M + 1) / 2;
    const int nblk  = (npair + AWPB - 1) / AWPB;
    const int gblk  = (M + 31) / 32;

    // Layer 1: agg1 -> hbuf (fp16); gemm1: hbuf <- fp16(relu(aggH + b1 + xh@lw1)) in place
    agg_kernel<<<nblk, 512, 0, stream>>>(xh, epack, start, w1, hbuf, M);
    mfma_gemm<1><<<gblk, 256, 0, stream>>>(xh, w1t, b1, hbuf, nullptr, hbuf, M);

    // Layer 2: agg2 -> xh-space (dead); gemm2: out = agg2 + b2 + hbuf@lw2
    agg_kernel<<<nblk, 512, 0, stream>>>(hbuf, epack, start, w2, xh, M);
    mfma_gemm<0><<<gblk, 256, 0, stream>>>(hbuf, w2t, b2, xh, out, nullptr, M);
}